// Round 8
// baseline (76.546 us; speedup 1.0000x reference)
//
#include <hip/hip_runtime.h>

#define LOG2E 1.44269504088896340736f

__device__ __forceinline__ float fexp2(float x){
#if __has_builtin(__builtin_amdgcn_exp2f)
  return __builtin_amdgcn_exp2f(x);
#else
  return exp2f(x);
#endif
}
__device__ __forceinline__ float frcp(float x){
#if __has_builtin(__builtin_amdgcn_rcpf)
  return __builtin_amdgcn_rcpf(x);
#else
  return 1.0f/x;
#endif
}
__device__ __forceinline__ float tanh_fast(float x){
  float e = fexp2(x * (2.0f*LOG2E));
  return 1.0f - 2.0f*frcp(e + 1.0f);
}
__device__ __forceinline__ float4 fma4(float s, float4 w, float4 a){
  a.x = fmaf(s,w.x,a.x); a.y = fmaf(s,w.y,a.y);
  a.z = fmaf(s,w.z,a.z); a.w = fmaf(s,w.w,a.w);
  return a;
}

// Rank-3 attention, ONE WAVE PER BLOCK (zero barriers).
// Block = (branch, batch-pair): bid&3 selects branch, bid>>2 selects the
// 2-batch group. Staging write -> broadcast read is same-wave (lgkmcnt
// only, no __syncthreads). h written straight to hbuf.
// S[q,k] = g(q)^T M g(k), M = Aq Ak^T (3x3, scale*log2e folded), g=(x,y,1).
// h = mean_q(Ex/E)*wv0 + mean_q(Ey/E)*wv1 + vb. Lane owns rows lane, lane+64.
__global__ __launch_bounds__(64, 8)
void attn_kernel(const float* __restrict__ state,
    const float* __restrict__ W_RT, const float* __restrict__ b_RT,
    const float* __restrict__ W_OB, const float* __restrict__ b_OB,
    const float* __restrict__ W_RS, const float* __restrict__ b_RS,
    const float* __restrict__ W_TG, const float* __restrict__ b_TG,
    float* __restrict__ hbuf)
{
  __shared__ float4 su4[128];                              // (ux,uy,uz,xk)
  __shared__ float  sy[128] __attribute__((aligned(16)));  // yk
  const int bid  = blockIdx.x;
  const int br   = bid & 3;
  const int b0   = (bid >> 2) * 2;      // 2 batches per block
  const int lane = threadIdx.x;         // 0..63

  const float* W;  const float* bb;  int dq;
  if      (br == 0) { W = W_RT; bb = b_RT; dq = 8;  }
  else if (br == 1) { W = W_OB; bb = b_OB; dq = 8;  }
  else if (br == 2) { W = W_RS; bb = b_RS; dq = 8;  }
  else              { W = W_TG; bb = b_TG; dq = 16; }
  const int D  = 4*dq;
  const int dv = 2*dq;
  const int n0 = br * 128;
  const int hoff = br * 16;
  const float qs = LOG2E * (dq==8 ? 0.35355339059327373f : 0.25f); // log2e/sqrt(dk)

  // M = Aq Ak^T * qs — uniform scalar-ish loop, once per block.
  float M00=0,M01=0,M02=0,M10=0,M11=0,M12=0,M20=0,M21=0,M22=0;
  for (int d=0; d<dq; ++d) {
    float aq0 = W[d], aq1 = W[D+d], aq2 = bb[d];
    float ak0 = W[dq+d], ak1 = W[D+dq+d], ak2 = bb[dq+d];
    M00 = fmaf(aq0,ak0,M00); M01 = fmaf(aq0,ak1,M01); M02 = fmaf(aq0,ak2,M02);
    M10 = fmaf(aq1,ak0,M10); M11 = fmaf(aq1,ak1,M11); M12 = fmaf(aq1,ak2,M12);
    M20 = fmaf(aq2,ak0,M20); M21 = fmaf(aq2,ak1,M21); M22 = fmaf(aq2,ak2,M22);
  }
  M00*=qs; M01*=qs; M02*=qs; M10*=qs; M11*=qs; M12*=qs; M20*=qs; M21*=qs; M22*=qs;

  float wv0 = 0.f, wv1 = 0.f, vb = 0.f;
  if (lane < dv) { wv0 = W[2*dq+lane]; wv1 = W[D+2*dq+lane]; vb = bb[2*dq+lane]; }

  #pragma unroll 1
  for (int e = 0; e < 2; ++e) {
    const int b = b0 + e;
    const float* sp = state + ((size_t)b*512 + (size_t)(n0 + lane))*3;
    float x0 = sp[0],   y0 = sp[1];
    float x1 = sp[192], y1 = sp[193];   // +64 rows * 3 floats

    // stage u_k for own 2 k's (same-wave: no barrier needed)
    {
      float4 uA, uB;
      uA.x = fmaf(M00,x0, fmaf(M01,y0, M02));
      uA.y = fmaf(M10,x0, fmaf(M11,y0, M12));
      uA.z = fmaf(M20,x0, fmaf(M21,y0, M22));
      uA.w = x0;
      uB.x = fmaf(M00,x1, fmaf(M01,y1, M02));
      uB.y = fmaf(M10,x1, fmaf(M11,y1, M12));
      uB.z = fmaf(M20,x1, fmaf(M21,y1, M22));
      uB.w = x1;
      su4[lane]    = uA;  sy[lane]    = y0;
      su4[lane+64] = uB;  sy[lane+64] = y1;
    }

    float E0=0.f, Ex0=0.f, Ey0=0.f, E1=0.f, Ex1=0.f, Ey1=0.f;
    const float4* Y4 = (const float4*)sy;
    #pragma unroll 2
    for (int k4=0; k4<32; ++k4) {
      float4 yq = Y4[k4];
      #pragma unroll
      for (int j=0; j<4; ++j) {
        float4 u = su4[4*k4+j];
        float yk = (j==0)?yq.x : (j==1)?yq.y : (j==2)?yq.z : yq.w;
        float s0 = fmaf(x0,u.x, fmaf(y0,u.y, u.z));
        float s1 = fmaf(x1,u.x, fmaf(y1,u.y, u.z));
        float e0 = fexp2(s0), e1 = fexp2(s1);
        E0 += e0;                 E1 += e1;
        Ex0 = fmaf(e0,u.w,Ex0);   Ex1 = fmaf(e1,u.w,Ex1);
        Ey0 = fmaf(e0,yk,Ey0);    Ey1 = fmaf(e1,yk,Ey1);
      }
    }
    float r0 = frcp(E0), r1 = frcp(E1);
    float gx = fmaf(Ex0,r0, Ex1*r1);
    float gy = fmaf(Ey0,r0, Ey1*r1);
    #pragma unroll
    for (int m=1; m<64; m<<=1) {
      gx += __shfl_xor(gx, m, 64);
      gy += __shfl_xor(gy, m, 64);
    }
    gx *= 0.0078125f;  // mean over 128 rows
    gy *= 0.0078125f;
    if (lane < dv)
      hbuf[(size_t)b*80 + hoff + lane] = fmaf(gx, wv0, fmaf(gy, wv1, vb));
  }
}

// MLP: 80 -> 256 (tanh) -> 256 (tanh) -> 1.  (unchanged from R6 — measured
// ~11 us.) 16 batch rows per block, grid 256 = 1 block/CU. Thread t:
// unit-quad q=t>>2 (float4 coalesced weight loads), row-group rg=t&3
// (rows 4rg..4rg+3). Depth-4 register prefetch, static i4&3 indexing.
__global__ __launch_bounds__(256, 1)
void mlp_kernel(const float* __restrict__ hbuf,
    const float* __restrict__ W1, const float* __restrict__ b1,
    const float* __restrict__ W2, const float* __restrict__ b2,
    const float* __restrict__ W3, const float* __restrict__ b3,
    float* __restrict__ out)
{
  __shared__ float sHin[16][84];
  __shared__ float sH1[16][260];
  __shared__ float sRed[4][16];
  const int t  = threadIdx.x;
  const int b0 = blockIdx.x * 16;
  const int q  = t >> 2;
  const int rg = t & 3;
  const int wave = t >> 6;

  for (int i = t; i < 16*80; i += 256) sHin[i/80][i%80] = hbuf[(size_t)b0*80 + i];
  __syncthreads();

  const float4* W1v = (const float4*)W1;
  const float4* W2v = (const float4*)W2;

  // ---- layer 1: 80 -> 256, tanh (depth-4 pipeline) ----
  float4 acc[4];
  {
    float4 bq = ((const float4*)b1)[q];
    acc[0]=bq; acc[1]=bq; acc[2]=bq; acc[3]=bq;
    float4 wb[4][4];
    #pragma unroll
    for (int p=0; p<4; ++p)
      #pragma unroll
      for (int jj=0; jj<4; ++jj) wb[p][jj] = W1v[(size_t)(4*p+jj)*64 + q];
    #pragma unroll 4
    for (int i4 = 0; i4 < 16; ++i4) {
      float4 w0=wb[i4&3][0], w1=wb[i4&3][1], w2=wb[i4&3][2], w3=wb[i4&3][3];
      #pragma unroll
      for (int jj=0; jj<4; ++jj) wb[i4&3][jj] = W1v[(size_t)((i4+4)*4+jj)*64 + q];
      #pragma unroll
      for (int r=0; r<4; ++r) {
        float4 h = *(const float4*)&sHin[4*rg+r][i4*4];
        acc[r] = fma4(h.x,w0, fma4(h.y,w1, fma4(h.z,w2, fma4(h.w,w3, acc[r]))));
      }
    }
    #pragma unroll
    for (int i4 = 16; i4 < 20; ++i4) {
      float4 w0=wb[i4&3][0], w1=wb[i4&3][1], w2=wb[i4&3][2], w3=wb[i4&3][3];
      #pragma unroll
      for (int r=0; r<4; ++r) {
        float4 h = *(const float4*)&sHin[4*rg+r][i4*4];
        acc[r] = fma4(h.x,w0, fma4(h.y,w1, fma4(h.z,w2, fma4(h.w,w3, acc[r]))));
      }
    }
  }
  #pragma unroll
  for (int r=0; r<4; ++r) {
    float4 o;
    o.x=tanh_fast(acc[r].x); o.y=tanh_fast(acc[r].y);
    o.z=tanh_fast(acc[r].z); o.w=tanh_fast(acc[r].w);
    *(float4*)&sH1[4*rg+r][4*q] = o;
  }
  __syncthreads();

  // ---- layer 2: 256 -> 256, tanh (depth-4 pipeline) ----
  float4 acc2[4];
  {
    float4 bq = ((const float4*)b2)[q];
    acc2[0]=bq; acc2[1]=bq; acc2[2]=bq; acc2[3]=bq;
    float4 wb[4][4];
    #pragma unroll
    for (int p=0; p<4; ++p)
      #pragma unroll
      for (int jj=0; jj<4; ++jj) wb[p][jj] = W2v[(size_t)(4*p+jj)*64 + q];
    #pragma unroll 4
    for (int i4 = 0; i4 < 60; ++i4) {
      float4 w0=wb[i4&3][0], w1=wb[i4&3][1], w2=wb[i4&3][2], w3=wb[i4&3][3];
      #pragma unroll
      for (int jj=0; jj<4; ++jj) wb[i4&3][jj] = W2v[(size_t)((i4+4)*4+jj)*64 + q];
      #pragma unroll
      for (int r=0; r<4; ++r) {
        float4 h = *(const float4*)&sH1[4*rg+r][i4*4];
        acc2[r] = fma4(h.x,w0, fma4(h.y,w1, fma4(h.z,w2, fma4(h.w,w3, acc2[r]))));
      }
    }
    #pragma unroll
    for (int i4 = 60; i4 < 64; ++i4) {
      float4 w0=wb[i4&3][0], w1=wb[i4&3][1], w2=wb[i4&3][2], w3=wb[i4&3][3];
      #pragma unroll
      for (int r=0; r<4; ++r) {
        float4 h = *(const float4*)&sH1[4*rg+r][i4*4];
        acc2[r] = fma4(h.x,w0, fma4(h.y,w1, fma4(h.z,w2, fma4(h.w,w3, acc2[r]))));
      }
    }
  }

  // ---- layer 3: 256 -> 1 ----
  float4 w3v = ((const float4*)W3)[q];
  float p[4];
  #pragma unroll
  for (int r=0; r<4; ++r) {
    p[r] = tanh_fast(acc2[r].x)*w3v.x + tanh_fast(acc2[r].y)*w3v.y
         + tanh_fast(acc2[r].z)*w3v.z + tanh_fast(acc2[r].w)*w3v.w;
  }
  #pragma unroll
  for (int m=4; m<64; m<<=1) {
    #pragma unroll
    for (int r=0; r<4; ++r) p[r] += __shfl_xor(p[r], m, 64);
  }
  if ((t & 63) == rg) {
    #pragma unroll
    for (int r=0; r<4; ++r) sRed[wave][4*rg + r] = p[r];
  }
  __syncthreads();
  if (t < 16)
    out[b0 + t] = sRed[0][t] + sRed[1][t] + sRed[2][t] + sRed[3][t] + b3[0];
}

extern "C" void kernel_launch(void* const* d_in, const int* in_sizes, int n_in,
                              void* d_out, int out_size, void* d_ws, size_t ws_size,
                              hipStream_t stream) {
  const float* state = (const float*)d_in[0];
  const float* W_RT = (const float*)d_in[5];
  const float* b_RT = (const float*)d_in[6];
  const float* W_OB = (const float*)d_in[7];
  const float* b_OB = (const float*)d_in[8];
  const float* W_RS = (const float*)d_in[9];
  const float* b_RS = (const float*)d_in[10];
  const float* W_TG = (const float*)d_in[11];
  const float* b_TG = (const float*)d_in[12];
  const float* W1 = (const float*)d_in[13];
  const float* b1 = (const float*)d_in[14];
  const float* W2 = (const float*)d_in[15];
  const float* b2 = (const float*)d_in[16];
  const float* W3 = (const float*)d_in[17];
  const float* b3 = (const float*)d_in[18];

  float* hbuf = (float*)d_ws;   // 4096 x 80 f32 = 1.31 MB

  attn_kernel<<<8192, 64, 0, stream>>>(state,
      W_RT, b_RT, W_OB, b_OB, W_RS, b_RS, W_TG, b_TG, hbuf);
  mlp_kernel<<<256, 256, 0, stream>>>(hbuf, W1, b1, W2, b2, W3, b3,
      (float*)d_out);
}

// Round 9
// 72.715 us; speedup vs baseline: 1.0527x; 1.0527x over previous
//
#include <hip/hip_runtime.h>

#define LOG2E 1.44269504088896340736f

__device__ __forceinline__ float fexp2(float x){
#if __has_builtin(__builtin_amdgcn_exp2f)
  return __builtin_amdgcn_exp2f(x);
#else
  return exp2f(x);
#endif
}
__device__ __forceinline__ float frcp(float x){
#if __has_builtin(__builtin_amdgcn_rcpf)
  return __builtin_amdgcn_rcpf(x);
#else
  return 1.0f/x;
#endif
}
__device__ __forceinline__ float tanh_fast(float x){
  float e = fexp2(x * (2.0f*LOG2E));
  return 1.0f - 2.0f*frcp(e + 1.0f);
}
__device__ __forceinline__ float4 fma4(float s, float4 w, float4 a){
  a.x = fmaf(s,w.x,a.x); a.y = fmaf(s,w.y,a.y);
  a.z = fmaf(s,w.z,a.z); a.w = fmaf(s,w.w,a.w);
  return a;
}

// Rank-3 attention. 256-thread block, wave = branch (compile-time DQ/DV),
// NB=2 batches per block, ZERO barriers (each wave owns its LDS slice and
// writes its h-slice straight to hbuf). Grid 2048 = 8 blocks/CU = 32
// waves/CU. Default launch bounds: VGPR ~56 (R6-measured) allows full
// wave occupancy; do NOT cap VGPRs (R7 lesson: 32-VGPR squeeze +40% instrs).
// S[q,k] = g(q)^T M g(k), M = Aq Ak^T (3x3, scale*log2e folded), g=(x,y,1).
// h = mean_q(Ex/E)*wv0 + mean_q(Ey/E)*wv1 + vb. Lane owns rows lane, lane+64.
template<int DQ, int DV, int NB>
__device__ __forceinline__ void branch_run(
    const float* __restrict__ state, int b0, int n0,
    const float* __restrict__ W, const float* __restrict__ bias,
    float4* __restrict__ su4, float* __restrict__ sy,
    int hoff, float* __restrict__ hbuf, int lane)
{
  const int D = 4*DQ;
  const float qs = LOG2E * (DQ==8 ? 0.35355339059327373f : 0.25f); // log2e/sqrt(dk)

  // M = Aq Ak^T * qs — once per block, uniform operands.
  float M00=0,M01=0,M02=0,M10=0,M11=0,M12=0,M20=0,M21=0,M22=0;
  #pragma unroll
  for (int d=0; d<DQ; ++d) {
    float aq0 = W[d], aq1 = W[D+d], aq2 = bias[d];
    float ak0 = W[DQ+d], ak1 = W[D+DQ+d], ak2 = bias[DQ+d];
    M00 = fmaf(aq0,ak0,M00); M01 = fmaf(aq0,ak1,M01); M02 = fmaf(aq0,ak2,M02);
    M10 = fmaf(aq1,ak0,M10); M11 = fmaf(aq1,ak1,M11); M12 = fmaf(aq1,ak2,M12);
    M20 = fmaf(aq2,ak0,M20); M21 = fmaf(aq2,ak1,M21); M22 = fmaf(aq2,ak2,M22);
  }
  M00*=qs; M01*=qs; M02*=qs; M10*=qs; M11*=qs; M12*=qs; M20*=qs; M21*=qs; M22*=qs;

  float wv0 = 0.f, wv1 = 0.f, vb = 0.f;
  if (lane < DV) { wv0 = W[2*DQ+lane]; wv1 = W[D+2*DQ+lane]; vb = bias[2*DQ+lane]; }

  #pragma unroll 1
  for (int e = 0; e < NB; ++e) {
    const int b = b0 + e;
    const float* sp = state + ((size_t)b*512 + (size_t)(n0 + lane))*3;
    float x0 = sp[0],   y0 = sp[1];
    float x1 = sp[192], y1 = sp[193];   // +64 rows * 3 floats

    // stage u_k = M g(k) for own 2 k's (same-wave producer/consumer:
    // compiler's lgkmcnt ordering suffices, no barrier)
    {
      float4 uA, uB;
      uA.x = fmaf(M00,x0, fmaf(M01,y0, M02));
      uA.y = fmaf(M10,x0, fmaf(M11,y0, M12));
      uA.z = fmaf(M20,x0, fmaf(M21,y0, M22));
      uA.w = x0;
      uB.x = fmaf(M00,x1, fmaf(M01,y1, M02));
      uB.y = fmaf(M10,x1, fmaf(M11,y1, M12));
      uB.z = fmaf(M20,x1, fmaf(M21,y1, M22));
      uB.w = x1;
      su4[lane]    = uA;  sy[lane]    = y0;
      su4[lane+64] = uB;  sy[lane+64] = y1;
    }

    float E0=0.f, Ex0=0.f, Ey0=0.f, E1=0.f, Ex1=0.f, Ey1=0.f;
    const float4* Y4 = (const float4*)sy;
    #pragma unroll 2
    for (int k4=0; k4<32; ++k4) {
      float4 yq = Y4[k4];
      #pragma unroll
      for (int j=0; j<4; ++j) {
        float4 u = su4[4*k4+j];
        float yk = (j==0)?yq.x : (j==1)?yq.y : (j==2)?yq.z : yq.w;
        float s0 = fmaf(x0,u.x, fmaf(y0,u.y, u.z));
        float s1 = fmaf(x1,u.x, fmaf(y1,u.y, u.z));
        float e0 = fexp2(s0), e1 = fexp2(s1);
        E0 += e0;                 E1 += e1;
        Ex0 = fmaf(e0,u.w,Ex0);   Ex1 = fmaf(e1,u.w,Ex1);
        Ey0 = fmaf(e0,yk,Ey0);    Ey1 = fmaf(e1,yk,Ey1);
      }
    }
    float r0 = frcp(E0), r1 = frcp(E1);
    float gx = fmaf(Ex0,r0, Ex1*r1);
    float gy = fmaf(Ey0,r0, Ey1*r1);
    #pragma unroll
    for (int m=1; m<64; m<<=1) {
      gx += __shfl_xor(gx, m, 64);
      gy += __shfl_xor(gy, m, 64);
    }
    gx *= 0.0078125f;  // mean over 128 rows
    gy *= 0.0078125f;
    if (lane < DV)
      hbuf[(size_t)b*80 + hoff + lane] = fmaf(gx, wv0, fmaf(gy, wv1, vb));
  }
}

__global__ __launch_bounds__(256)
void attn_kernel(const float* __restrict__ state,
    const float* __restrict__ W_RT, const float* __restrict__ b_RT,
    const float* __restrict__ W_OB, const float* __restrict__ b_OB,
    const float* __restrict__ W_RS, const float* __restrict__ b_RS,
    const float* __restrict__ W_TG, const float* __restrict__ b_TG,
    float* __restrict__ hbuf)
{
  __shared__ float4 su4[4][128];
  __shared__ float  sy[4][128] __attribute__((aligned(16)));
  const int b0   = blockIdx.x * 2;    // 2 batches per block
  const int wave = threadIdx.x >> 6;
  const int lane = threadIdx.x & 63;

  const float* W;  const float* bb;
  if      (wave == 0) { W = W_RT; bb = b_RT; }
  else if (wave == 1) { W = W_OB; bb = b_OB; }
  else if (wave == 2) { W = W_RS; bb = b_RS; }
  else                { W = W_TG; bb = b_TG; }
  const int n0 = wave * 128;
  const int hoff = wave * 16;   // RT:0 OB:16 RS:32 TG:48..79

  if (wave < 3)
    branch_run<8 ,16,2>(state, b0, n0, W, bb, su4[wave], sy[wave],
                        hoff, hbuf, lane);
  else
    branch_run<16,32,2>(state, b0, n0, W, bb, su4[wave], sy[wave],
                        hoff, hbuf, lane);
}

// MLP: 80 -> 256 (tanh) -> 256 (tanh) -> 1.  (unchanged — measured ~11 us.)
// 16 batch rows per block, grid 256 = 1 block/CU. Thread t: unit-quad
// q=t>>2 (float4 coalesced weight loads), row-group rg=t&3 (rows
// 4rg..4rg+3). Depth-4 register prefetch, static i4&3 indexing.
__global__ __launch_bounds__(256, 1)
void mlp_kernel(const float* __restrict__ hbuf,
    const float* __restrict__ W1, const float* __restrict__ b1,
    const float* __restrict__ W2, const float* __restrict__ b2,
    const float* __restrict__ W3, const float* __restrict__ b3,
    float* __restrict__ out)
{
  __shared__ float sHin[16][84];
  __shared__ float sH1[16][260];
  __shared__ float sRed[4][16];
  const int t  = threadIdx.x;
  const int b0 = blockIdx.x * 16;
  const int q  = t >> 2;
  const int rg = t & 3;
  const int wave = t >> 6;

  for (int i = t; i < 16*80; i += 256) sHin[i/80][i%80] = hbuf[(size_t)b0*80 + i];
  __syncthreads();

  const float4* W1v = (const float4*)W1;
  const float4* W2v = (const float4*)W2;

  // ---- layer 1: 80 -> 256, tanh (depth-4 pipeline) ----
  float4 acc[4];
  {
    float4 bq = ((const float4*)b1)[q];
    acc[0]=bq; acc[1]=bq; acc[2]=bq; acc[3]=bq;
    float4 wb[4][4];
    #pragma unroll
    for (int p=0; p<4; ++p)
      #pragma unroll
      for (int jj=0; jj<4; ++jj) wb[p][jj] = W1v[(size_t)(4*p+jj)*64 + q];
    #pragma unroll 4
    for (int i4 = 0; i4 < 16; ++i4) {
      float4 w0=wb[i4&3][0], w1=wb[i4&3][1], w2=wb[i4&3][2], w3=wb[i4&3][3];
      #pragma unroll
      for (int jj=0; jj<4; ++jj) wb[i4&3][jj] = W1v[(size_t)((i4+4)*4+jj)*64 + q];
      #pragma unroll
      for (int r=0; r<4; ++r) {
        float4 h = *(const float4*)&sHin[4*rg+r][i4*4];
        acc[r] = fma4(h.x,w0, fma4(h.y,w1, fma4(h.z,w2, fma4(h.w,w3, acc[r]))));
      }
    }
    #pragma unroll
    for (int i4 = 16; i4 < 20; ++i4) {
      float4 w0=wb[i4&3][0], w1=wb[i4&3][1], w2=wb[i4&3][2], w3=wb[i4&3][3];
      #pragma unroll
      for (int r=0; r<4; ++r) {
        float4 h = *(const float4*)&sHin[4*rg+r][i4*4];
        acc[r] = fma4(h.x,w0, fma4(h.y,w1, fma4(h.z,w2, fma4(h.w,w3, acc[r]))));
      }
    }
  }
  #pragma unroll
  for (int r=0; r<4; ++r) {
    float4 o;
    o.x=tanh_fast(acc[r].x); o.y=tanh_fast(acc[r].y);
    o.z=tanh_fast(acc[r].z); o.w=tanh_fast(acc[r].w);
    *(float4*)&sH1[4*rg+r][4*q] = o;
  }
  __syncthreads();

  // ---- layer 2: 256 -> 256, tanh (depth-4 pipeline) ----
  float4 acc2[4];
  {
    float4 bq = ((const float4*)b2)[q];
    acc2[0]=bq; acc2[1]=bq; acc2[2]=bq; acc2[3]=bq;
    float4 wb[4][4];
    #pragma unroll
    for (int p=0; p<4; ++p)
      #pragma unroll
      for (int jj=0; jj<4; ++jj) wb[p][jj] = W2v[(size_t)(4*p+jj)*64 + q];
    #pragma unroll 4
    for (int i4 = 0; i4 < 60; ++i4) {
      float4 w0=wb[i4&3][0], w1=wb[i4&3][1], w2=wb[i4&3][2], w3=wb[i4&3][3];
      #pragma unroll
      for (int jj=0; jj<4; ++jj) wb[i4&3][jj] = W2v[(size_t)((i4+4)*4+jj)*64 + q];
      #pragma unroll
      for (int r=0; r<4; ++r) {
        float4 h = *(const float4*)&sH1[4*rg+r][i4*4];
        acc2[r] = fma4(h.x,w0, fma4(h.y,w1, fma4(h.z,w2, fma4(h.w,w3, acc2[r]))));
      }
    }
    #pragma unroll
    for (int i4 = 60; i4 < 64; ++i4) {
      float4 w0=wb[i4&3][0], w1=wb[i4&3][1], w2=wb[i4&3][2], w3=wb[i4&3][3];
      #pragma unroll
      for (int r=0; r<4; ++r) {
        float4 h = *(const float4*)&sH1[4*rg+r][i4*4];
        acc2[r] = fma4(h.x,w0, fma4(h.y,w1, fma4(h.z,w2, fma4(h.w,w3, acc2[r]))));
      }
    }
  }

  // ---- layer 3: 256 -> 1 ----
  float4 w3v = ((const float4*)W3)[q];
  float p[4];
  #pragma unroll
  for (int r=0; r<4; ++r) {
    p[r] = tanh_fast(acc2[r].x)*w3v.x + tanh_fast(acc2[r].y)*w3v.y
         + tanh_fast(acc2[r].z)*w3v.z + tanh_fast(acc2[r].w)*w3v.w;
  }
  #pragma unroll
  for (int m=4; m<64; m<<=1) {
    #pragma unroll
    for (int r=0; r<4; ++r) p[r] += __shfl_xor(p[r], m, 64);
  }
  if ((t & 63) == rg) {
    #pragma unroll
    for (int r=0; r<4; ++r) sRed[wave][4*rg + r] = p[r];
  }
  __syncthreads();
  if (t < 16)
    out[b0 + t] = sRed[0][t] + sRed[1][t] + sRed[2][t] + sRed[3][t] + b3[0];
}

extern "C" void kernel_launch(void* const* d_in, const int* in_sizes, int n_in,
                              void* d_out, int out_size, void* d_ws, size_t ws_size,
                              hipStream_t stream) {
  const float* state = (const float*)d_in[0];
  const float* W_RT = (const float*)d_in[5];
  const float* b_RT = (const float*)d_in[6];
  const float* W_OB = (const float*)d_in[7];
  const float* b_OB = (const float*)d_in[8];
  const float* W_RS = (const float*)d_in[9];
  const float* b_RS = (const float*)d_in[10];
  const float* W_TG = (const float*)d_in[11];
  const float* b_TG = (const float*)d_in[12];
  const float* W1 = (const float*)d_in[13];
  const float* b1 = (const float*)d_in[14];
  const float* W2 = (const float*)d_in[15];
  const float* b2 = (const float*)d_in[16];
  const float* W3 = (const float*)d_in[17];
  const float* b3 = (const float*)d_in[18];

  float* hbuf = (float*)d_ws;   // 4096 x 80 f32 = 1.31 MB

  attn_kernel<<<2048, 256, 0, stream>>>(state,
      W_RT, b_RT, W_OB, b_OB, W_RS, b_RS, W_TG, b_TG, hbuf);
  mlp_kernel<<<256, 256, 0, stream>>>(hbuf, W1, b1, W2, b2, W3, b3,
      (float*)d_out);
}

// Round 10
// 67.346 us; speedup vs baseline: 1.1366x; 1.0797x over previous
//
#include <hip/hip_runtime.h>

#define LOG2E 1.44269504088896340736f

__device__ __forceinline__ float fexp2(float x){
#if __has_builtin(__builtin_amdgcn_exp2f)
  return __builtin_amdgcn_exp2f(x);
#else
  return exp2f(x);
#endif
}
__device__ __forceinline__ float frcp(float x){
#if __has_builtin(__builtin_amdgcn_rcpf)
  return __builtin_amdgcn_rcpf(x);
#else
  return 1.0f/x;
#endif
}
__device__ __forceinline__ float tanh_fast(float x){
  float e = fexp2(x * (2.0f*LOG2E));
  return 1.0f - 2.0f*frcp(e + 1.0f);
}
__device__ __forceinline__ float4 fma4(float s, float4 w, float4 a){
  a.x = fmaf(s,w.x,a.x); a.y = fmaf(s,w.y,a.y);
  a.z = fmaf(s,w.z,a.z); a.w = fmaf(s,w.w,a.w);
  return a;
}

// Rank-3 attention. 256-thread block, wave = branch, NB=2 batches/block,
// zero barriers (each wave owns its LDS slice; same-wave write->read).
// KEY (R9): LDS broadcasts only raw geometry (xk,yk) = 8 B/k; the 3x3
// bilinear form is folded into per-ROW registers (A,B,C) = M^T g(q):
//   S[q,k] = A*xk + B*yk + C     (M = Aq Ak^T * qs*log2e, g=(x,y,1))
// This cuts LDS-pipe demand from 1.25 to 0.5 ds_read_b128 per k-iter —
// the per-CU LDS pipe (shared by 4 SIMDs) was the binding resource at
// ~90% busy in R2..R8 (R7->R8: more waves made it SLOWER).
// h = mean_q(Ex/E)*wv0 + mean_q(Ey/E)*wv1 + vb. Lane owns rows lane, lane+64.
template<int DQ, int DV, int NB>
__device__ __forceinline__ void branch_run(
    const float* __restrict__ state, int b0, int n0,
    const float* __restrict__ W, const float* __restrict__ bias,
    float2* __restrict__ sg, int hoff, float* __restrict__ hbuf, int lane)
{
  const int D = 4*DQ;
  const float qs = LOG2E * (DQ==8 ? 0.35355339059327373f : 0.25f); // log2e/sqrt(dk)

  // M = Aq Ak^T * qs — once per block, uniform operands.
  float M00=0,M01=0,M02=0,M10=0,M11=0,M12=0,M20=0,M21=0,M22=0;
  #pragma unroll
  for (int d=0; d<DQ; ++d) {
    float aq0 = W[d], aq1 = W[D+d], aq2 = bias[d];
    float ak0 = W[DQ+d], ak1 = W[D+DQ+d], ak2 = bias[DQ+d];
    M00 = fmaf(aq0,ak0,M00); M01 = fmaf(aq0,ak1,M01); M02 = fmaf(aq0,ak2,M02);
    M10 = fmaf(aq1,ak0,M10); M11 = fmaf(aq1,ak1,M11); M12 = fmaf(aq1,ak2,M12);
    M20 = fmaf(aq2,ak0,M20); M21 = fmaf(aq2,ak1,M21); M22 = fmaf(aq2,ak2,M22);
  }
  M00*=qs; M01*=qs; M02*=qs; M10*=qs; M11*=qs; M12*=qs; M20*=qs; M21*=qs; M22*=qs;

  float wv0 = 0.f, wv1 = 0.f, vb = 0.f;
  if (lane < DV) { wv0 = W[2*DQ+lane]; wv1 = W[D+2*DQ+lane]; vb = bias[2*DQ+lane]; }

  #pragma unroll 1
  for (int e = 0; e < NB; ++e) {
    const int b = b0 + e;
    const float* sp = state + ((size_t)b*512 + (size_t)(n0 + lane))*3;
    float x0 = sp[0],   y0 = sp[1];
    float x1 = sp[192], y1 = sp[193];   // +64 rows * 3 floats

    // stage raw (x,y) for own 2 k's; same-wave producer/consumer (lgkmcnt).
    float2 gA; gA.x = x0; gA.y = y0;
    float2 gB; gB.x = x1; gB.y = y1;
    sg[lane]    = gA;
    sg[lane+64] = gB;

    // per-row query coefficients: (A,B,C) = M^T g(row)
    float A0 = fmaf(x0,M00, fmaf(y0,M10, M20));
    float B0 = fmaf(x0,M01, fmaf(y0,M11, M21));
    float C0 = fmaf(x0,M02, fmaf(y0,M12, M22));
    float A1 = fmaf(x1,M00, fmaf(y1,M10, M20));
    float B1 = fmaf(x1,M01, fmaf(y1,M11, M21));
    float C1 = fmaf(x1,M02, fmaf(y1,M12, M22));

    float E0=0.f, Ex0=0.f, Ey0=0.f, E1=0.f, Ex1=0.f, Ey1=0.f;
    const float4* G4 = (const float4*)sg;   // (x[2p],y[2p],x[2p+1],y[2p+1])
    #pragma unroll 4
    for (int p = 0; p < 64; ++p) {          // 2 k per float4
      float4 g = G4[p];
      {
        float sA = fmaf(A0,g.x, fmaf(B0,g.y, C0));
        float sB = fmaf(A1,g.x, fmaf(B1,g.y, C1));
        float eA = fexp2(sA), eB = fexp2(sB);
        E0 += eA;  Ex0 = fmaf(eA,g.x,Ex0);  Ey0 = fmaf(eA,g.y,Ey0);
        E1 += eB;  Ex1 = fmaf(eB,g.x,Ex1);  Ey1 = fmaf(eB,g.y,Ey1);
      }
      {
        float sA = fmaf(A0,g.z, fmaf(B0,g.w, C0));
        float sB = fmaf(A1,g.z, fmaf(B1,g.w, C1));
        float eA = fexp2(sA), eB = fexp2(sB);
        E0 += eA;  Ex0 = fmaf(eA,g.z,Ex0);  Ey0 = fmaf(eA,g.w,Ey0);
        E1 += eB;  Ex1 = fmaf(eB,g.z,Ex1);  Ey1 = fmaf(eB,g.w,Ey1);
      }
    }
    float r0 = frcp(E0), r1 = frcp(E1);
    float gx = fmaf(Ex0,r0, Ex1*r1);
    float gy = fmaf(Ey0,r0, Ey1*r1);
    #pragma unroll
    for (int m=1; m<64; m<<=1) {
      gx += __shfl_xor(gx, m, 64);
      gy += __shfl_xor(gy, m, 64);
    }
    gx *= 0.0078125f;  // mean over 128 rows
    gy *= 0.0078125f;
    if (lane < DV)
      hbuf[(size_t)b*80 + hoff + lane] = fmaf(gx, wv0, fmaf(gy, wv1, vb));
  }
}

__global__ __launch_bounds__(256)
void attn_kernel(const float* __restrict__ state,
    const float* __restrict__ W_RT, const float* __restrict__ b_RT,
    const float* __restrict__ W_OB, const float* __restrict__ b_OB,
    const float* __restrict__ W_RS, const float* __restrict__ b_RS,
    const float* __restrict__ W_TG, const float* __restrict__ b_TG,
    float* __restrict__ hbuf)
{
  __shared__ float2 sg[4][128] __attribute__((aligned(16)));
  const int b0   = blockIdx.x * 2;    // 2 batches per block
  const int wave = threadIdx.x >> 6;
  const int lane = threadIdx.x & 63;

  const float* W;  const float* bb;
  if      (wave == 0) { W = W_RT; bb = b_RT; }
  else if (wave == 1) { W = W_OB; bb = b_OB; }
  else if (wave == 2) { W = W_RS; bb = b_RS; }
  else                { W = W_TG; bb = b_TG; }
  const int n0 = wave * 128;
  const int hoff = wave * 16;   // RT:0 OB:16 RS:32 TG:48..79

  if (wave < 3)
    branch_run<8 ,16,2>(state, b0, n0, W, bb, sg[wave], hoff, hbuf, lane);
  else
    branch_run<16,32,2>(state, b0, n0, W, bb, sg[wave], hoff, hbuf, lane);
}

// MLP: 80 -> 256 (tanh) -> 256 (tanh) -> 1.  (unchanged — measured ~10.6 us.)
// 16 batch rows per block, grid 256 = 1 block/CU. Thread t: unit-quad
// q=t>>2 (float4 coalesced weight loads), row-group rg=t&3 (rows
// 4rg..4rg+3). Depth-4 register prefetch, static i4&3 indexing.
__global__ __launch_bounds__(256, 1)
void mlp_kernel(const float* __restrict__ hbuf,
    const float* __restrict__ W1, const float* __restrict__ b1,
    const float* __restrict__ W2, const float* __restrict__ b2,
    const float* __restrict__ W3, const float* __restrict__ b3,
    float* __restrict__ out)
{
  __shared__ float sHin[16][84];
  __shared__ float sH1[16][260];
  __shared__ float sRed[4][16];
  const int t  = threadIdx.x;
  const int b0 = blockIdx.x * 16;
  const int q  = t >> 2;
  const int rg = t & 3;
  const int wave = t >> 6;

  for (int i = t; i < 16*80; i += 256) sHin[i/80][i%80] = hbuf[(size_t)b0*80 + i];
  __syncthreads();

  const float4* W1v = (const float4*)W1;
  const float4* W2v = (const float4*)W2;

  // ---- layer 1: 80 -> 256, tanh (depth-4 pipeline) ----
  float4 acc[4];
  {
    float4 bq = ((const float4*)b1)[q];
    acc[0]=bq; acc[1]=bq; acc[2]=bq; acc[3]=bq;
    float4 wb[4][4];
    #pragma unroll
    for (int p=0; p<4; ++p)
      #pragma unroll
      for (int jj=0; jj<4; ++jj) wb[p][jj] = W1v[(size_t)(4*p+jj)*64 + q];
    #pragma unroll 4
    for (int i4 = 0; i4 < 16; ++i4) {
      float4 w0=wb[i4&3][0], w1=wb[i4&3][1], w2=wb[i4&3][2], w3=wb[i4&3][3];
      #pragma unroll
      for (int jj=0; jj<4; ++jj) wb[i4&3][jj] = W1v[(size_t)((i4+4)*4+jj)*64 + q];
      #pragma unroll
      for (int r=0; r<4; ++r) {
        float4 h = *(const float4*)&sHin[4*rg+r][i4*4];
        acc[r] = fma4(h.x,w0, fma4(h.y,w1, fma4(h.z,w2, fma4(h.w,w3, acc[r]))));
      }
    }
    #pragma unroll
    for (int i4 = 16; i4 < 20; ++i4) {
      float4 w0=wb[i4&3][0], w1=wb[i4&3][1], w2=wb[i4&3][2], w3=wb[i4&3][3];
      #pragma unroll
      for (int r=0; r<4; ++r) {
        float4 h = *(const float4*)&sHin[4*rg+r][i4*4];
        acc[r] = fma4(h.x,w0, fma4(h.y,w1, fma4(h.z,w2, fma4(h.w,w3, acc[r]))));
      }
    }
  }
  #pragma unroll
  for (int r=0; r<4; ++r) {
    float4 o;
    o.x=tanh_fast(acc[r].x); o.y=tanh_fast(acc[r].y);
    o.z=tanh_fast(acc[r].z); o.w=tanh_fast(acc[r].w);
    *(float4*)&sH1[4*rg+r][4*q] = o;
  }
  __syncthreads();

  // ---- layer 2: 256 -> 256, tanh (depth-4 pipeline) ----
  float4 acc2[4];
  {
    float4 bq = ((const float4*)b2)[q];
    acc2[0]=bq; acc2[1]=bq; acc2[2]=bq; acc2[3]=bq;
    float4 wb[4][4];
    #pragma unroll
    for (int p=0; p<4; ++p)
      #pragma unroll
      for (int jj=0; jj<4; ++jj) wb[p][jj] = W2v[(size_t)(4*p+jj)*64 + q];
    #pragma unroll 4
    for (int i4 = 0; i4 < 60; ++i4) {
      float4 w0=wb[i4&3][0], w1=wb[i4&3][1], w2=wb[i4&3][2], w3=wb[i4&3][3];
      #pragma unroll
      for (int jj=0; jj<4; ++jj) wb[i4&3][jj] = W2v[(size_t)((i4+4)*4+jj)*64 + q];
      #pragma unroll
      for (int r=0; r<4; ++r) {
        float4 h = *(const float4*)&sH1[4*rg+r][i4*4];
        acc2[r] = fma4(h.x,w0, fma4(h.y,w1, fma4(h.z,w2, fma4(h.w,w3, acc2[r]))));
      }
    }
    #pragma unroll
    for (int i4 = 60; i4 < 64; ++i4) {
      float4 w0=wb[i4&3][0], w1=wb[i4&3][1], w2=wb[i4&3][2], w3=wb[i4&3][3];
      #pragma unroll
      for (int r=0; r<4; ++r) {
        float4 h = *(const float4*)&sH1[4*rg+r][i4*4];
        acc2[r] = fma4(h.x,w0, fma4(h.y,w1, fma4(h.z,w2, fma4(h.w,w3, acc2[r]))));
      }
    }
  }

  // ---- layer 3: 256 -> 1 ----
  float4 w3v = ((const float4*)W3)[q];
  float p[4];
  #pragma unroll
  for (int r=0; r<4; ++r) {
    p[r] = tanh_fast(acc2[r].x)*w3v.x + tanh_fast(acc2[r].y)*w3v.y
         + tanh_fast(acc2[r].z)*w3v.z + tanh_fast(acc2[r].w)*w3v.w;
  }
  #pragma unroll
  for (int m=4; m<64; m<<=1) {
    #pragma unroll
    for (int r=0; r<4; ++r) p[r] += __shfl_xor(p[r], m, 64);
  }
  if ((t & 63) == rg) {
    #pragma unroll
    for (int r=0; r<4; ++r) sRed[wave][4*rg + r] = p[r];
  }
  __syncthreads();
  if (t < 16)
    out[b0 + t] = sRed[0][t] + sRed[1][t] + sRed[2][t] + sRed[3][t] + b3[0];
}

extern "C" void kernel_launch(void* const* d_in, const int* in_sizes, int n_in,
                              void* d_out, int out_size, void* d_ws, size_t ws_size,
                              hipStream_t stream) {
  const float* state = (const float*)d_in[0];
  const float* W_RT = (const float*)d_in[5];
  const float* b_RT = (const float*)d_in[6];
  const float* W_OB = (const float*)d_in[7];
  const float* b_OB = (const float*)d_in[8];
  const float* W_RS = (const float*)d_in[9];
  const float* b_RS = (const float*)d_in[10];
  const float* W_TG = (const float*)d_in[11];
  const float* b_TG = (const float*)d_in[12];
  const float* W1 = (const float*)d_in[13];
  const float* b1 = (const float*)d_in[14];
  const float* W2 = (const float*)d_in[15];
  const float* b2 = (const float*)d_in[16];
  const float* W3 = (const float*)d_in[17];
  const float* b3 = (const float*)d_in[18];

  float* hbuf = (float*)d_ws;   // 4096 x 80 f32 = 1.31 MB

  attn_kernel<<<2048, 256, 0, stream>>>(state,
      W_RT, b_RT, W_OB, b_OB, W_RS, b_RS, W_TG, b_TG, hbuf);
  mlp_kernel<<<256, 256, 0, stream>>>(hbuf, W1, b1, W2, b2, W3, b3,
      (float*)d_out);
}